// Round 3
// baseline (1717.427 us; speedup 1.0000x reference)
//
#include <hip/hip_runtime.h>
#include <math.h>

#define TOKENS   8192
#define DMODEL   1024
#define HDIM     2048
#define NEXP     8
#define NSH      2
#define NGRP     10
#define R_ROUTED 16384
#define R_TOTAL  32768

typedef float  f32x4  __attribute__((ext_vector_type(4)));
typedef __bf16 bf16x8 __attribute__((ext_vector_type(8)));
typedef unsigned short u16x8 __attribute__((ext_vector_type(8)));

typedef __attribute__((address_space(1))) const void as1_void;
typedef __attribute__((address_space(3))) void as3_void;
#define GLOAD16(g, l) __builtin_amdgcn_global_load_lds((as1_void*)(g), (as3_void*)(l), 16, 0, 0)

__device__ __forceinline__ unsigned short f2bf(float f) {
  unsigned int u = __float_as_uint(f);
  u += 0x7fffu + ((u >> 16) & 1u);
  return (unsigned short)(u >> 16);
}

// ---------------- conversion kernels ----------------

__global__ __launch_bounds__(256) void convert_x_kernel(const float* __restrict__ x,
                                                        unsigned short* __restrict__ xb) {
  int i = blockIdx.x * blockDim.x + threadIdx.x;
  const float4 v = reinterpret_cast<const float4*>(x)[i];
  ushort4 o;
  o.x = f2bf(v.x); o.y = f2bf(v.y); o.z = f2bf(v.z); o.w = f2bf(v.w);
  reinterpret_cast<ushort4*>(xb)[i] = o;
}

// transpose fp32 (R x C) -> bf16 (C x R), 64x64 tiles, vectorized both sides
__global__ __launch_bounds__(256) void transpose_cvt64_kernel(const float* __restrict__ src,
                                                              unsigned short* __restrict__ dst,
                                                              int R, int C) {
  __shared__ float tile[64][65];
  const size_t mat = blockIdx.z;
  src += mat * (size_t)R * C;
  dst += mat * (size_t)R * C;
  const int c0 = blockIdx.x * 64, r0 = blockIdx.y * 64;
  const int tid = threadIdx.x;
  const int tx = tid & 15, ty = tid >> 4;     // 16 x 16
  #pragma unroll
  for (int rr = 0; rr < 4; ++rr) {
    const int row = ty + rr * 16;
    const float4 v = *reinterpret_cast<const float4*>(&src[(size_t)(r0 + row) * C + c0 + tx * 4]);
    tile[row][tx * 4 + 0] = v.x;
    tile[row][tx * 4 + 1] = v.y;
    tile[row][tx * 4 + 2] = v.z;
    tile[row][tx * 4 + 3] = v.w;
  }
  __syncthreads();
  const int oc = tid >> 2, og = tid & 3;      // col 0..63, r-quarter 0..3
  u16x8 u0, u1;
  #pragma unroll
  for (int e = 0; e < 8; ++e) u0[e] = f2bf(tile[og * 16 + e][oc]);
  #pragma unroll
  for (int e = 0; e < 8; ++e) u1[e] = f2bf(tile[og * 16 + 8 + e][oc]);
  unsigned short* dp = &dst[(size_t)(c0 + oc) * R + r0 + og * 16];
  *reinterpret_cast<u16x8*>(dp) = u0;
  *reinterpret_cast<u16x8*>(dp + 8) = u1;
}

// ---------------- gating / routing ----------------

__global__ __launch_bounds__(64) void gate_kernel(const float* __restrict__ x,
                                                  const float* __restrict__ gw,
                                                  const float* __restrict__ gb,
                                                  int* __restrict__ topk_idx,
                                                  float* __restrict__ topk_w,
                                                  int* __restrict__ counts) {
  const int t = blockIdx.x;
  const int lane = threadIdx.x;
  const float* xr = x + (size_t)t * DMODEL;
  float acc[NEXP];
  #pragma unroll
  for (int e = 0; e < NEXP; ++e) acc[e] = 0.f;
  for (int d = lane; d < DMODEL; d += 64) {
    const float xv = xr[d];
    const float* g = gw + (size_t)d * NEXP;
    #pragma unroll
    for (int e = 0; e < NEXP; ++e) acc[e] += xv * g[e];
  }
  #pragma unroll
  for (int e = 0; e < NEXP; ++e) {
    float v = acc[e];
    v += __shfl_down(v, 32); v += __shfl_down(v, 16); v += __shfl_down(v, 8);
    v += __shfl_down(v, 4);  v += __shfl_down(v, 2);  v += __shfl_down(v, 1);
    acc[e] = v;
  }
  if (lane == 0) {
    float p[NEXP];
    float mx = -1e30f;
    #pragma unroll
    for (int e = 0; e < NEXP; ++e) { acc[e] += gb[e]; mx = fmaxf(mx, acc[e]); }
    float s = 0.f;
    #pragma unroll
    for (int e = 0; e < NEXP; ++e) { p[e] = expf(acc[e] - mx); s += p[e]; }
    const float inv = 1.f / s;
    #pragma unroll
    for (int e = 0; e < NEXP; ++e) p[e] *= inv;
    int i1 = 0; float v1 = p[0];
    #pragma unroll
    for (int e = 1; e < NEXP; ++e) if (p[e] > v1) { v1 = p[e]; i1 = e; }
    int i2 = -1; float v2 = -1e30f;
    #pragma unroll
    for (int e = 0; e < NEXP; ++e) if (e != i1 && p[e] > v2) { v2 = p[e]; i2 = e; }
    topk_idx[t * 2 + 0] = i1; topk_w[t * 2 + 0] = v1;
    topk_idx[t * 2 + 1] = i2; topk_w[t * 2 + 1] = v2;
    atomicAdd(&counts[i1], 1);
    atomicAdd(&counts[i2], 1);
  }
}

__global__ void offs_kernel(const int* __restrict__ counts, int* __restrict__ offs) {
  if (threadIdx.x == 0 && blockIdx.x == 0) {
    int cum = 0;
    for (int e = 0; e < NEXP; ++e) { offs[e] = cum; cum += counts[e]; }
    offs[8] = R_ROUTED;
    offs[9] = R_ROUTED + TOKENS;
    offs[10] = R_TOTAL;
  }
}

__global__ __launch_bounds__(256) void scatter_kernel(const int* __restrict__ topk_idx,
                                                      const float* __restrict__ topk_w,
                                                      const int* __restrict__ offs,
                                                      int* __restrict__ cursors,
                                                      int* __restrict__ row_token,
                                                      float* __restrict__ row_coef) {
  const int t = blockIdx.x * blockDim.x + threadIdx.x;
  if (t >= TOKENS) return;
  #pragma unroll
  for (int k = 0; k < 2; ++k) {
    const int e = topk_idx[t * 2 + k];
    const int pos = atomicAdd(&cursors[e], 1);
    const int r = offs[e] + pos;
    row_token[r] = t;
    row_coef[r] = topk_w[t * 2 + k];
  }
  row_token[R_ROUTED + t] = t;          row_coef[R_ROUTED + t] = 0.5f;
  row_token[R_ROUTED + TOKENS + t] = t; row_coef[R_ROUTED + TOKENS + t] = 0.5f;
}

// ---------------- grouped GEMM 1 (pipelined): glu = silu(X W1 + b1) * (X W2 + b2) ----
// BM=256, BN=128, BK=64, 512 threads (8 waves, 2M x 4N), double-buffered LDS,
// counted vmcnt(8) pipeline: stage tile kt+2 issued before MFMA ks=1 of tile kt.
// LDS slot (row, j) holds global k-chunk j ^ (row&7) (T2 swizzle, involution).

__global__ __launch_bounds__(512, 2) void gemm1_kernel(
    const unsigned short* __restrict__ xb,
    const unsigned short* __restrict__ w1t,
    const unsigned short* __restrict__ w2t,
    const float* __restrict__ rb1, const float* __restrict__ sb1,
    const float* __restrict__ rb2, const float* __restrict__ sb2,
    const int* __restrict__ offs,
    const int* __restrict__ row_token,
    unsigned short* __restrict__ glu) {
  const int g = blockIdx.z;
  const int off_g = offs[g];
  const int n_g = offs[g + 1] - off_g;
  const int m0 = blockIdx.x * 256;
  if (m0 >= n_g) return;
  const int n0 = blockIdx.y * 128;

  __shared__ __align__(16) unsigned short Abuf[2][256 * 64];
  __shared__ __align__(16) unsigned short B1buf[2][128 * 64];
  __shared__ __align__(16) unsigned short B2buf[2][128 * 64];

  const int tid = threadIdx.x;
  const int lane = tid & 63;
  const int wid = tid >> 6;
  const int wm = wid >> 2, wn = wid & 3;
  const int l15 = lane & 15, kq = lane >> 4;

  const unsigned short* w1g = w1t + (size_t)g * HDIM * DMODEL;
  const unsigned short* w2g = w2t + (size_t)g * HDIM * DMODEL;

  // staging address precompute (source pre-swizzled; LDS dest linear per wave)
  const unsigned short* srcA[4]; int dA[4];
  #pragma unroll
  for (int r = 0; r < 4; ++r) {
    const int flat = r * 512 + tid, row = flat >> 3, j = flat & 7;
    int ar = m0 + row; if (ar > n_g - 1) ar = n_g - 1;
    srcA[r] = xb + (size_t)row_token[off_g + ar] * DMODEL + ((j ^ (row & 7)) << 3);
    dA[r] = (r * 512 + (tid & ~63)) << 3;
  }
  const unsigned short* srcB1[2]; const unsigned short* srcB2[2]; int dB[2];
  #pragma unroll
  for (int r = 0; r < 2; ++r) {
    const int flat = r * 512 + tid, row = flat >> 3, j = flat & 7;
    const size_t o = (size_t)(n0 + row) * DMODEL + ((j ^ (row & 7)) << 3);
    srcB1[r] = w1g + o; srcB2[r] = w2g + o;
    dB[r] = (r * 512 + (tid & ~63)) << 3;
  }

  f32x4 acc1[8][2], acc2[8][2];
  const f32x4 zero = {0.f, 0.f, 0.f, 0.f};
  #pragma unroll
  for (int i = 0; i < 8; ++i)
    #pragma unroll
    for (int j = 0; j < 2; ++j) { acc1[i][j] = zero; acc2[i][j] = zero; }

  auto stage = [&](int cur, int k0) {
    #pragma unroll
    for (int r = 0; r < 4; ++r) GLOAD16(srcA[r] + k0, &Abuf[cur][dA[r]]);
    #pragma unroll
    for (int r = 0; r < 2; ++r) {
      GLOAD16(srcB1[r] + k0, &B1buf[cur][dB[r]]);
      GLOAD16(srcB2[r] + k0, &B2buf[cur][dB[r]]);
    }
  };
  auto frag_read = [&](int cur, int kc, bf16x8* a, bf16x8* p, bf16x8* q) {
    #pragma unroll
    for (int mi = 0; mi < 8; ++mi) {
      const int row = wm * 128 + mi * 16 + l15;
      a[mi] = *reinterpret_cast<const bf16x8*>(&Abuf[cur][row * 64 + ((kc ^ (row & 7)) << 3)]);
    }
    #pragma unroll
    for (int ni = 0; ni < 2; ++ni) {
      const int row = wn * 32 + ni * 16 + l15;
      p[ni] = *reinterpret_cast<const bf16x8*>(&B1buf[cur][row * 64 + ((kc ^ (row & 7)) << 3)]);
      q[ni] = *reinterpret_cast<const bf16x8*>(&B2buf[cur][row * 64 + ((kc ^ (row & 7)) << 3)]);
    }
  };
  auto mfma_blk = [&](const bf16x8* a, const bf16x8* p, const bf16x8* q) {
    #pragma unroll
    for (int mi = 0; mi < 8; ++mi)
      #pragma unroll
      for (int ni = 0; ni < 2; ++ni) {
        acc1[mi][ni] = __builtin_amdgcn_mfma_f32_16x16x32_bf16(a[mi], p[ni], acc1[mi][ni], 0, 0, 0);
        acc2[mi][ni] = __builtin_amdgcn_mfma_f32_16x16x32_bf16(a[mi], q[ni], acc2[mi][ni], 0, 0, 0);
      }
  };

  // prologue: tiles 0 and 1 in flight; wait for tile 0 (8 newest outstanding)
  stage(0, 0);
  stage(1, 64);
  asm volatile("s_waitcnt vmcnt(8)" ::: "memory");
  __builtin_amdgcn_s_barrier();
  asm volatile("" ::: "memory");

  for (int kt = 0; kt < 16; ++kt) {
    const int cur = kt & 1;
    bf16x8 a0[8], p0[2], q0[2];
    frag_read(cur, kq, a0, p0, q0);             // ks=0
    mfma_blk(a0, p0, q0);
    bf16x8 a1[8], p1[2], q1[2];
    frag_read(cur, 4 + kq, a1, p1, q1);         // ks=1
    asm volatile("s_waitcnt lgkmcnt(0)" ::: "memory");   // all reads of buf[cur] done
    __builtin_amdgcn_s_barrier();                         // every wave done reading
    asm volatile("" ::: "memory");
    if (kt + 2 < 16) stage(cur, (kt + 2) * 64);           // overwrite buf[cur] w/ tile kt+2
    __builtin_amdgcn_s_setprio(1);
    mfma_blk(a1, p1, q1);
    __builtin_amdgcn_s_setprio(0);
    if (kt + 2 < 16) asm volatile("s_waitcnt vmcnt(8)" ::: "memory");  // tile kt+1 resident
    else             asm volatile("s_waitcnt vmcnt(0)" ::: "memory");
    __builtin_amdgcn_s_barrier();
    asm volatile("" ::: "memory");
  }

  const float* b1p = (g < NEXP) ? (rb1 + (size_t)g * HDIM) : (sb1 + (size_t)(g - NEXP) * HDIM);
  const float* b2p = (g < NEXP) ? (rb2 + (size_t)g * HDIM) : (sb2 + (size_t)(g - NEXP) * HDIM);

  #pragma unroll
  for (int mi = 0; mi < 8; ++mi) {
    #pragma unroll
    for (int r = 0; r < 4; ++r) {
      const int m = m0 + wm * 128 + mi * 16 + kq * 4 + r;
      if (m < n_g) {
        #pragma unroll
        for (int ni = 0; ni < 2; ++ni) {
          const int n = n0 + wn * 32 + ni * 16 + l15;
          const float x1 = acc1[mi][ni][r] + b1p[n];
          const float x2 = acc2[mi][ni][r] + b2p[n];
          glu[(size_t)(off_g + m) * HDIM + n] = f2bf((x1 / (1.f + expf(-x1))) * x2);
        }
      }
    }
  }
}

// ---------------- grouped GEMM 2 (pipelined): out += coef * (glu W3 + b3) -------------
// BM=256, BN=256, BK=64, 512 threads (8 waves, 2M x 4N), same pipeline.

__global__ __launch_bounds__(512, 2) void gemm2_kernel(
    const unsigned short* __restrict__ glu,
    const unsigned short* __restrict__ w3t,
    const float* __restrict__ rb3, const float* __restrict__ sb3,
    const int* __restrict__ offs,
    const int* __restrict__ row_token,
    const float* __restrict__ row_coef,
    float* __restrict__ out) {
  const int g = blockIdx.z;
  const int off_g = offs[g];
  const int n_g = offs[g + 1] - off_g;
  const int m0 = blockIdx.x * 256;
  if (m0 >= n_g) return;
  const int n0 = blockIdx.y * 256;

  __shared__ __align__(16) unsigned short Abuf[2][256 * 64];
  __shared__ __align__(16) unsigned short Bbuf[2][256 * 64];

  const int tid = threadIdx.x;
  const int lane = tid & 63;
  const int wid = tid >> 6;
  const int wm = wid >> 2, wn = wid & 3;
  const int l15 = lane & 15, kq = lane >> 4;

  const unsigned short* w3g = w3t + (size_t)g * DMODEL * HDIM;

  const unsigned short* srcA[4]; const unsigned short* srcB[4]; int dAB[4];
  #pragma unroll
  for (int r = 0; r < 4; ++r) {
    const int flat = r * 512 + tid, row = flat >> 3, j = flat & 7;
    int ar = m0 + row; if (ar > n_g - 1) ar = n_g - 1;
    srcA[r] = glu + (size_t)(off_g + ar) * HDIM + ((j ^ (row & 7)) << 3);
    srcB[r] = w3g + (size_t)(n0 + row) * HDIM + ((j ^ (row & 7)) << 3);
    dAB[r] = (r * 512 + (tid & ~63)) << 3;
  }

  f32x4 acc[8][4];
  const f32x4 zero = {0.f, 0.f, 0.f, 0.f};
  #pragma unroll
  for (int i = 0; i < 8; ++i)
    #pragma unroll
    for (int j = 0; j < 4; ++j) acc[i][j] = zero;

  auto stage = [&](int cur, int k0) {
    #pragma unroll
    for (int r = 0; r < 4; ++r) GLOAD16(srcA[r] + k0, &Abuf[cur][dAB[r]]);
    #pragma unroll
    for (int r = 0; r < 4; ++r) GLOAD16(srcB[r] + k0, &Bbuf[cur][dAB[r]]);
  };
  auto frag_read = [&](int cur, int kc, bf16x8* a, bf16x8* b) {
    #pragma unroll
    for (int mi = 0; mi < 8; ++mi) {
      const int row = wm * 128 + mi * 16 + l15;
      a[mi] = *reinterpret_cast<const bf16x8*>(&Abuf[cur][row * 64 + ((kc ^ (row & 7)) << 3)]);
    }
    #pragma unroll
    for (int ni = 0; ni < 4; ++ni) {
      const int row = wn * 64 + ni * 16 + l15;
      b[ni] = *reinterpret_cast<const bf16x8*>(&Bbuf[cur][row * 64 + ((kc ^ (row & 7)) << 3)]);
    }
  };
  auto mfma_blk = [&](const bf16x8* a, const bf16x8* b) {
    #pragma unroll
    for (int mi = 0; mi < 8; ++mi)
      #pragma unroll
      for (int ni = 0; ni < 4; ++ni)
        acc[mi][ni] = __builtin_amdgcn_mfma_f32_16x16x32_bf16(a[mi], b[ni], acc[mi][ni], 0, 0, 0);
  };

  stage(0, 0);
  stage(1, 64);
  asm volatile("s_waitcnt vmcnt(8)" ::: "memory");
  __builtin_amdgcn_s_barrier();
  asm volatile("" ::: "memory");

  for (int kt = 0; kt < 32; ++kt) {
    const int cur = kt & 1;
    bf16x8 a0[8], b0[4];
    frag_read(cur, kq, a0, b0);
    mfma_blk(a0, b0);
    bf16x8 a1[8], b1[4];
    frag_read(cur, 4 + kq, a1, b1);
    asm volatile("s_waitcnt lgkmcnt(0)" ::: "memory");
    __builtin_amdgcn_s_barrier();
    asm volatile("" ::: "memory");
    if (kt + 2 < 32) stage(cur, (kt + 2) * 64);
    __builtin_amdgcn_s_setprio(1);
    mfma_blk(a1, b1);
    __builtin_amdgcn_s_setprio(0);
    if (kt + 2 < 32) asm volatile("s_waitcnt vmcnt(8)" ::: "memory");
    else             asm volatile("s_waitcnt vmcnt(0)" ::: "memory");
    __builtin_amdgcn_s_barrier();
    asm volatile("" ::: "memory");
  }

  const float* b3p = (g < NEXP) ? (rb3 + (size_t)g * DMODEL) : (sb3 + (size_t)(g - NEXP) * DMODEL);

  #pragma unroll
  for (int mi = 0; mi < 8; ++mi) {
    #pragma unroll
    for (int r = 0; r < 4; ++r) {
      const int m = m0 + wm * 128 + mi * 16 + kq * 4 + r;
      if (m < n_g) {
        const int t = row_token[off_g + m];
        const float cf = row_coef[off_g + m];
        float* orow = out + (size_t)t * DMODEL;
        #pragma unroll
        for (int ni = 0; ni < 4; ++ni) {
          const int n = n0 + wn * 64 + ni * 16 + l15;
          atomicAdd(&orow[n], (acc[mi][ni][r] + b3p[n]) * cf);
        }
      }
    }
  }
}

// ---------------- launch ----------------

extern "C" void kernel_launch(void* const* d_in, const int* in_sizes, int n_in,
                              void* d_out, int out_size, void* d_ws, size_t ws_size,
                              hipStream_t stream) {
  const float* x      = (const float*)d_in[0];
  const float* gate_w = (const float*)d_in[1];
  const float* gate_b = (const float*)d_in[2];
  const float* rw1    = (const float*)d_in[3];
  const float* rb1    = (const float*)d_in[4];
  const float* rw2    = (const float*)d_in[5];
  const float* rb2    = (const float*)d_in[6];
  const float* rw3    = (const float*)d_in[7];
  const float* rb3    = (const float*)d_in[8];
  const float* sw1    = (const float*)d_in[9];
  const float* sb1    = (const float*)d_in[10];
  const float* sw2    = (const float*)d_in[11];
  const float* sb2    = (const float*)d_in[12];
  const float* sw3    = (const float*)d_in[13];
  const float* sb3    = (const float*)d_in[14];
  float* out = (float*)d_out;

  // workspace layout
  const size_t XB_OFF   = 0;
  const size_t W1T_OFF  = XB_OFF  + (size_t)TOKENS * DMODEL * 2;
  const size_t W2T_OFF  = W1T_OFF + (size_t)NGRP * HDIM * DMODEL * 2;
  const size_t W3T_OFF  = W2T_OFF + (size_t)NGRP * HDIM * DMODEL * 2;
  const size_t GLU_OFF  = W3T_OFF + (size_t)NGRP * DMODEL * HDIM * 2;
  const size_t RTOK_OFF = GLU_OFF + (size_t)R_TOTAL * HDIM * 2;
  const size_t RCOE_OFF = RTOK_OFF + (size_t)R_TOTAL * 4;
  const size_t TKI_OFF  = RCOE_OFF + (size_t)R_TOTAL * 4;
  const size_t TKW_OFF  = TKI_OFF + (size_t)TOKENS * 2 * 4;
  const size_t META_OFF = TKW_OFF + (size_t)TOKENS * 2 * 4;
  const size_t NEED     = META_OFF + 256;
  if (ws_size < NEED) return;

  char* ws = (char*)d_ws;
  unsigned short* xb   = (unsigned short*)(ws + XB_OFF);
  unsigned short* w1t  = (unsigned short*)(ws + W1T_OFF);
  unsigned short* w2t  = (unsigned short*)(ws + W2T_OFF);
  unsigned short* w3t  = (unsigned short*)(ws + W3T_OFF);
  unsigned short* glu  = (unsigned short*)(ws + GLU_OFF);
  int*   row_token = (int*)(ws + RTOK_OFF);
  float* row_coef  = (float*)(ws + RCOE_OFF);
  int*   topk_idx  = (int*)(ws + TKI_OFF);
  float* topk_w    = (float*)(ws + TKW_OFF);
  int*   counts    = (int*)(ws + META_OFF);
  int*   offs      = counts + 16;
  int*   cursors   = counts + 32;

  hipMemsetAsync(counts, 0, 192, stream);
  hipMemsetAsync(out, 0, (size_t)TOKENS * DMODEL * sizeof(float), stream);

  convert_x_kernel<<<TOKENS * DMODEL / 4 / 256, 256, 0, stream>>>(x, xb);

  transpose_cvt64_kernel<<<dim3(HDIM / 64, DMODEL / 64, NEXP), 256, 0, stream>>>(rw1, w1t, DMODEL, HDIM);
  transpose_cvt64_kernel<<<dim3(HDIM / 64, DMODEL / 64, NSH), 256, 0, stream>>>(
      sw1, w1t + (size_t)NEXP * HDIM * DMODEL, DMODEL, HDIM);
  transpose_cvt64_kernel<<<dim3(HDIM / 64, DMODEL / 64, NEXP), 256, 0, stream>>>(rw2, w2t, DMODEL, HDIM);
  transpose_cvt64_kernel<<<dim3(HDIM / 64, DMODEL / 64, NSH), 256, 0, stream>>>(
      sw2, w2t + (size_t)NEXP * HDIM * DMODEL, DMODEL, HDIM);
  transpose_cvt64_kernel<<<dim3(DMODEL / 64, HDIM / 64, NEXP), 256, 0, stream>>>(rw3, w3t, HDIM, DMODEL);
  transpose_cvt64_kernel<<<dim3(DMODEL / 64, HDIM / 64, NSH), 256, 0, stream>>>(
      sw3, w3t + (size_t)NEXP * DMODEL * HDIM, HDIM, DMODEL);

  gate_kernel<<<TOKENS, 64, 0, stream>>>(x, gate_w, gate_b, topk_idx, topk_w, counts);
  offs_kernel<<<1, 64, 0, stream>>>(counts, offs);
  scatter_kernel<<<TOKENS / 256, 256, 0, stream>>>(topk_idx, topk_w, offs, cursors,
                                                   row_token, row_coef);

  gemm1_kernel<<<dim3(TOKENS / 256, HDIM / 128, NGRP), 512, 0, stream>>>(
      xb, w1t, w2t, rb1, sb1, rb2, sb2, offs, row_token, glu);
  gemm2_kernel<<<dim3(TOKENS / 256, DMODEL / 256, NGRP), 512, 0, stream>>>(
      glu, w3t, rb3, sb3, offs, row_token, row_coef, out);
}